// Round 1
// baseline (134.681 us; speedup 1.0000x reference)
//
#include <hip/hip_runtime.h>

typedef int   i32x8  __attribute__((ext_vector_type(8)));
typedef float f32x16 __attribute__((ext_vector_type(16)));

#define B_ROWS 4096
#define NROWS  8192
#define DDIM   512
// exp(sim/T) = exp2(sim * (1/T)/ln2), T=0.5 -> 2/ln2
#define SCALE2 2.8853900817779268f
// e8m0 scale 127 = 2^0 = 1.0 in every byte -> scaled MFMA == plain fp8 MFMA
#define SCL1   0x7f7f7f7f

// zq layout (NEW, for 32x32x64 MX fragments): per 32-row group (rg32 = row>>5),
// 16 KB = 8 k-groups (kg = k>>6) x 2 KB segments. Within a segment:
//   addr = ((k>>5)&1)*1024 + (row&31)*32 + (k&31)
// so an MFMA A/B fragment (row = lane&31, k = (lane>>5)*32 + 0..31) is the
// 32 CONTIGUOUS bytes at seg + lane*32. Staging and LDS copies stay linear.
// scratch: 64x64 grid of 128-float cells, each written EXACTLY once (row-parts of
// block (bi,bj) -> cell (bi,bj); col-parts -> cell (bj,bi)); no init, no atomics.

// ---------------- normalize: fp32 -> fp8 e4m3, 32-row blocks, LDS-repack ---------
__global__ __launch_bounds__(256) void normalize_kernel(
    const float* __restrict__ h1, const float* __restrict__ h2,
    unsigned char* __restrict__ zq, float* __restrict__ out) {
  __shared__ __align__(16) unsigned char tile[16384];
  if (blockIdx.x == 0 && threadIdx.x == 0) out[0] = 0.0f;

  const int wave = threadIdx.x >> 6;
  const int lane = threadIdx.x & 63;
  const int rb = blockIdx.x;            // 32-row group
  const int kg   = lane >> 3;           // k-group of 64 (lane covers k = lane*8..+7)
  const int h    = (lane >> 2) & 1;     // k-half of 32 within group
  const int koff = (lane & 3) * 8;      // byte offset within 32-byte row slice

  #pragma unroll
  for (int it = 0; it < 8; ++it) {
    const int r = it * 4 + wave;        // 0..31, one full row per wave
    const int row = rb * 32 + r;
    const float* src = (row < B_ROWS) ? (h1 + (size_t)row * DDIM)
                                      : (h2 + (size_t)(row - B_ROWS) * DDIM);
    float4 v0 = *(const float4*)(src + lane * 8);
    float4 v1 = *(const float4*)(src + lane * 8 + 4);
    float ss = v0.x*v0.x + v0.y*v0.y + v0.z*v0.z + v0.w*v0.w
             + v1.x*v1.x + v1.y*v1.y + v1.z*v1.z + v1.w*v1.w;
    #pragma unroll
    for (int m = 1; m <= 32; m <<= 1) ss += __shfl_xor(ss, m);
    float sc = 1.0f / fmaxf(sqrtf(ss), 1e-8f);
    int lo = 0, hi = 0;
    lo = __builtin_amdgcn_cvt_pk_fp8_f32(v0.x*sc, v0.y*sc, lo, 0);
    lo = __builtin_amdgcn_cvt_pk_fp8_f32(v0.z*sc, v0.w*sc, lo, 1);
    hi = __builtin_amdgcn_cvt_pk_fp8_f32(v1.x*sc, v1.y*sc, hi, 0);
    hi = __builtin_amdgcn_cvt_pk_fp8_f32(v1.z*sc, v1.w*sc, hi, 1);
    *(int2*)(tile + kg * 2048 + h * 1024 + r * 32 + koff) = make_int2(lo, hi);
  }
  __syncthreads();
  const size_t base = (size_t)rb * 16384;
  #pragma unroll
  for (int j = 0; j < 4; ++j)
    *(int4*)(zq + base + j * 4096 + threadIdx.x * 16) =
        *(const int4*)(tile + j * 4096 + threadIdx.x * 16);
}

// ---------------- fused sim GEMM (MX-fp8, unit scales) + exp + row-sum ------------
// 32x32x64 scaled MFMA at 2.3x the non-scaled fp8 rate (4686 vs 2047 TF ubench).
// Same 2-barrier K-quarter structure, same 128-reg / 4 blocks-per-CU budget
// (acc 2x2x16 = 64 VGPR, frags 4x8 = 32 VGPR — identical totals to R14).
__global__ __launch_bounds__(256, 4) void simexp_kernel(
    const unsigned char* __restrict__ zq, float* __restrict__ scratch,
    float* __restrict__ pos) {
  __shared__ __align__(16) unsigned char As[16384];  // 8 segs: s = rg32*2 + gl
  __shared__ __align__(16) unsigned char Bs[16384];
  __shared__ float rp[256];   // row partials: slot (lrow)*2 + wn
  __shared__ float cp[256];   // col partials: slot (lcol)*2 + wm

  const int tid  = threadIdx.x;
  const int wave = tid >> 6;
  const int lane = tid & 63;
  const int wm = wave >> 1, wn = wave & 1;
  const int l31 = lane & 31;
  const int hi5 = lane >> 5;

  // unrank triangular block index: t = bi*(bi+1)/2 + bj, bi >= bj
  int t  = blockIdx.x;
  int bi = (int)((sqrtf(8.0f * (float)t + 1.0f) - 1.0f) * 0.5f);
  while ((bi + 1) * (bi + 2) / 2 <= t) ++bi;
  while (bi * (bi + 1) / 2 > t) --bi;
  int bj = t - bi * (bi + 1) / 2;
  const int rowBlk = bi * 128;
  const int colBlk = bj * 128;
  const bool isDiag = (bi == bj);

  const unsigned char* aBase = zq + (size_t)bi * 65536;  // 4 rg32 x 8 kg x 2 KB
  const unsigned char* bBase = zq + (size_t)bj * 65536;

  f32x16 acc[2][2] = {};

  #pragma unroll
  for (int h = 0; h < 4; ++h) {              // K-quarter: kg = h*2, h*2+1
    if (h) __syncthreads();                  // waves done reading previous quarter
    #pragma unroll
    for (int i = 0; i < 4; ++i) {
      const int u = wave * 4 + i;            // 1 KB unit 0..15
      const int s = u >> 1;                  // LDS seg 0..7 = rg32*2 + gl
      const int rg32 = s >> 1, gl = s & 1;
      const size_t goff =
          (size_t)((rg32 * 8 + h * 2 + gl) * 2048 + (u & 1) * 1024 + lane * 16);
      const size_t loff = (size_t)(u * 1024 + lane * 16);
      __builtin_amdgcn_global_load_lds(
          (const __attribute__((address_space(1))) unsigned int*)(aBase + goff),
          (__attribute__((address_space(3))) unsigned int*)(As + loff), 16, 0, 0);
      __builtin_amdgcn_global_load_lds(
          (const __attribute__((address_space(1))) unsigned int*)(bBase + goff),
          (__attribute__((address_space(3))) unsigned int*)(Bs + loff), 16, 0, 0);
    }
    __syncthreads();                         // staged data visible

    #pragma unroll
    for (int gl = 0; gl < 2; ++gl) {         // K-64 step within quarter
      i32x8 afr[2], bfr[2];
      #pragma unroll
      for (int rt = 0; rt < 2; ++rt)
        afr[rt] = *(const i32x8*)(As + (size_t)((wm * 2 + rt) * 2 + gl) * 2048 + lane * 32);
      #pragma unroll
      for (int ct = 0; ct < 2; ++ct)
        bfr[ct] = *(const i32x8*)(Bs + (size_t)((wn * 2 + ct) * 2 + gl) * 2048 + lane * 32);
      #pragma unroll
      for (int rt = 0; rt < 2; ++rt)
        #pragma unroll
        for (int ct = 0; ct < 2; ++ct)
          acc[rt][ct] = __builtin_amdgcn_mfma_scale_f32_32x32x64_f8f6f4(
              afr[rt], bfr[ct], acc[rt][ct], 0, 0, 0, SCL1, 0, SCL1);
    }
  }

  // ---- epilogue: exp2 -> unique-slot plain LDS writes -> 1 barrier -> stores ----
  // 32x32 C/D layout: col = lane&31, row = (reg&3) + 8*(reg>>2) + 4*(lane>>5)
  const bool posBlk = (bi - bj == 32);  // contains the +B diagonal
  float colpart[2] = {0.f, 0.f};
  #pragma unroll
  for (int rt = 0; rt < 2; ++rt) {
    #pragma unroll
    for (int reg = 0; reg < 16; ++reg) {
      const int lrow = wm * 64 + rt * 32 + (reg & 3) + 8 * (reg >> 2) + 4 * hi5;
      const int grow = rowBlk + lrow;
      float s = 0.f;
      #pragma unroll
      for (int ct = 0; ct < 2; ++ct) {
        const int gcol = colBlk + wn * 64 + ct * 32 + l31;
        float sv = acc[rt][ct][reg];
        float e = exp2f(sv * SCALE2);
        if (isDiag && grow == gcol) e = 0.f;
        if (posBlk && grow - B_ROWS == gcol) pos[gcol] = sv;
        s += e;
        colpart[ct] += e;
      }
      s += __shfl_xor(s, 1);
      s += __shfl_xor(s, 2);
      s += __shfl_xor(s, 4);
      s += __shfl_xor(s, 8);
      s += __shfl_xor(s, 16);
      if (l31 == 0) rp[lrow * 2 + wn] = s;          // single writer per slot
    }
  }
  #pragma unroll
  for (int ct = 0; ct < 2; ++ct) {
    float c = colpart[ct];
    c += __shfl_xor(c, 32);                         // combine row-halves, same col
    if (hi5 == 0) cp[(wn * 64 + ct * 32 + l31) * 2 + wm] = c;  // single writer
  }
  __syncthreads();
  if (tid < 128) {
    scratch[(size_t)(bi * 64 + bj) * 128 + tid] = rp[tid * 2] + rp[tid * 2 + 1];
  } else if (!isDiag) {
    const int c = tid - 128;
    scratch[(size_t)(bj * 64 + bi) * 128 + c] = cp[c * 2] + cp[c * 2 + 1];
  }
}

// ---------------- finalize: rowsum from scratch; loss mean ------------------------
__global__ __launch_bounds__(256) void finalize_kernel(
    const float* __restrict__ scratch, const float* __restrict__ pos,
    float* __restrict__ out) {
  __shared__ float red[4];
  const int gid = blockIdx.x * 256 + threadIdx.x;
  const int band = gid >> 7, r = gid & 127;
  const float* base = scratch + (size_t)band * 64 * 128 + r;
  float s = 0.f;
  #pragma unroll 8
  for (int c = 0; c < 64; ++c) s += base[c * 128];
  float loss = __logf(s) - 2.0f * pos[gid & (B_ROWS - 1)];
  #pragma unroll
  for (int m = 1; m <= 32; m <<= 1) loss += __shfl_xor(loss, m);
  const int wave = threadIdx.x >> 6;
  const int lane = threadIdx.x & 63;
  if (lane == 0) red[wave] = loss;
  __syncthreads();
  if (threadIdx.x == 0)
    atomicAdd(out, (red[0] + red[1] + red[2] + red[3]) * (1.0f / NROWS));
}

extern "C" void kernel_launch(void* const* d_in, const int* in_sizes, int n_in,
                              void* d_out, int out_size, void* d_ws, size_t ws_size,
                              hipStream_t stream) {
  const float* h1 = (const float*)d_in[0];
  const float* h2 = (const float*)d_in[1];
  float* out = (float*)d_out;
  unsigned char* zq = (unsigned char*)d_ws;                        // 4 MiB fp8
  float* scratch = (float*)((char*)d_ws + (size_t)NROWS * DDIM);   // 2 MiB
  float* pos     = scratch + 64 * 64 * 128;                        // 16 KiB

  normalize_kernel<<<NROWS / 32, 256, 0, stream>>>(h1, h2, zq, out);
  simexp_kernel<<<64 * 65 / 2, 256, 0, stream>>>(zq, scratch, pos);
  finalize_kernel<<<NROWS / 256, 256, 0, stream>>>(scratch, pos, out);
}

// Round 2
// 105.970 us; speedup vs baseline: 1.2709x; 1.2709x over previous
//
#include <hip/hip_runtime.h>

typedef int   i32x4  __attribute__((ext_vector_type(4)));
typedef int   i32x8  __attribute__((ext_vector_type(8)));
typedef float f32x16 __attribute__((ext_vector_type(16)));

#define B_ROWS 4096
#define NROWS  8192
#define DDIM   512
// exp(sim/T) = exp2(sim * (1/T)/ln2), T=0.5 -> 2/ln2
#define SCALE2 2.8853900817779268f
// e8m0 scale 127 = 2^0 = 1.0 in every byte -> scaled MFMA == plain fp8 MFMA
#define SCL1   0x7f7f7f7f

// zq layout (v2, bank-conflict-free MX fragments): per 32-row group (rg32 =
// row>>5), 16 KB = 8 k-groups (kg = k>>6) x 2 KB segments. Within a segment,
// lane id l = (k>>5)*32 + (row&31); the lane's 32 fragment bytes are split:
//   bytes k%32 in [0,16)  at  seg +    0 + l*16 + (k&15)
//   bytes k%32 in [16,32) at  seg + 1024 + l*16 + (k&15)
// so an MFMA A/B fragment is TWO LINEAR ds_read_b128 (zero bank conflict),
// and global_load_lds staging stays linear (permutation baked into zq).
// scratch: 64x64 grid of 128-float cells, each written EXACTLY once (row-parts of
// block (bi,bj) -> cell (bi,bj); col-parts -> cell (bj,bi)); no init, no atomics.

// ---------------- normalize: fp32 -> fp8 e4m3, 32-row blocks, LDS-repack ---------
__global__ __launch_bounds__(256) void normalize_kernel(
    const float* __restrict__ h1, const float* __restrict__ h2,
    unsigned char* __restrict__ zq, float* __restrict__ out) {
  __shared__ __align__(16) unsigned char tile[16384];
  if (blockIdx.x == 0 && threadIdx.x == 0) out[0] = 0.0f;

  const int wave = threadIdx.x >> 6;
  const int lane = threadIdx.x & 63;
  const int rb = blockIdx.x;            // 32-row group
  // lane covers k = lane*8 .. lane*8+7
  const int kg = lane >> 3;             // k-group of 64
  const int q  = (lane >> 1) & 1;       // (k>>4)&1: which 16B half-page
  const int h  = (lane >> 2) & 1;       // (k>>5)&1: k-half of 32 (lane-id bit 5)
  const int k8 = (lane & 1) * 8;        // (k&15) byte offset within 16B unit

  #pragma unroll
  for (int it = 0; it < 8; ++it) {
    const int r = it * 4 + wave;        // 0..31, one full row per wave
    const int row = rb * 32 + r;
    const float* src = (row < B_ROWS) ? (h1 + (size_t)row * DDIM)
                                      : (h2 + (size_t)(row - B_ROWS) * DDIM);
    float4 v0 = *(const float4*)(src + lane * 8);
    float4 v1 = *(const float4*)(src + lane * 8 + 4);
    float ss = v0.x*v0.x + v0.y*v0.y + v0.z*v0.z + v0.w*v0.w
             + v1.x*v1.x + v1.y*v1.y + v1.z*v1.z + v1.w*v1.w;
    #pragma unroll
    for (int m = 1; m <= 32; m <<= 1) ss += __shfl_xor(ss, m);
    float sc = 1.0f / fmaxf(sqrtf(ss), 1e-8f);
    int lo = 0, hi = 0;
    lo = __builtin_amdgcn_cvt_pk_fp8_f32(v0.x*sc, v0.y*sc, lo, 0);
    lo = __builtin_amdgcn_cvt_pk_fp8_f32(v0.z*sc, v0.w*sc, lo, 1);
    hi = __builtin_amdgcn_cvt_pk_fp8_f32(v1.x*sc, v1.y*sc, hi, 0);
    hi = __builtin_amdgcn_cvt_pk_fp8_f32(v1.z*sc, v1.w*sc, hi, 1);
    *(int2*)(tile + kg * 2048 + q * 1024 + (h * 32 + r) * 16 + k8) =
        make_int2(lo, hi);
  }
  __syncthreads();
  const size_t base = (size_t)rb * 16384;
  #pragma unroll
  for (int j = 0; j < 4; ++j)
    *(int4*)(zq + base + j * 4096 + threadIdx.x * 16) =
        *(const int4*)(tile + j * 4096 + threadIdx.x * 16);
}

// ---------------- fused sim GEMM (MX-fp8, unit scales) + exp + row-sum ------------
// 32x32x64 scaled MFMA at ~2.3x the non-scaled fp8 rate (4686 vs 2047 TF ubench).
// R1 lesson: __launch_bounds__(256,4) (128-reg cap) forced 64 acc AGPR + 64 arch
// VGPR -> 287 MB of spill traffic, 121 us. Cap at 3 blocks/CU (170 regs) instead.
// Spill canary: WRITE_SIZE must be ~2 MB.
__global__ __launch_bounds__(256, 3) void simexp_kernel(
    const unsigned char* __restrict__ zq, float* __restrict__ scratch,
    float* __restrict__ pos) {
  __shared__ __align__(16) unsigned char As[16384];  // 8 segs: s = rg32*2 + gl
  __shared__ __align__(16) unsigned char Bs[16384];
  __shared__ float rp[256];   // row partials: slot (lrow)*2 + wn
  __shared__ float cp[256];   // col partials: slot (lcol)*2 + wm

  const int tid  = threadIdx.x;
  const int wave = tid >> 6;
  const int lane = tid & 63;
  const int wm = wave >> 1, wn = wave & 1;
  const int l31 = lane & 31;
  const int hi5 = lane >> 5;

  // unrank triangular block index: t = bi*(bi+1)/2 + bj, bi >= bj
  int t  = blockIdx.x;
  int bi = (int)((sqrtf(8.0f * (float)t + 1.0f) - 1.0f) * 0.5f);
  while ((bi + 1) * (bi + 2) / 2 <= t) ++bi;
  while (bi * (bi + 1) / 2 > t) --bi;
  int bj = t - bi * (bi + 1) / 2;
  const int rowBlk = bi * 128;
  const int colBlk = bj * 128;
  const bool isDiag = (bi == bj);

  const unsigned char* aBase = zq + (size_t)bi * 65536;  // 4 rg32 x 8 kg x 2 KB
  const unsigned char* bBase = zq + (size_t)bj * 65536;

  f32x16 acc[2][2] = {};

  #pragma unroll
  for (int h = 0; h < 4; ++h) {              // K-quarter: kg = h*2, h*2+1
    if (h) __syncthreads();                  // waves done reading previous quarter
    #pragma unroll
    for (int i = 0; i < 4; ++i) {
      const int u = wave * 4 + i;            // 1 KB unit 0..15
      const int s = u >> 1;                  // LDS seg 0..7 = rg32*2 + gl
      const int rg32 = s >> 1, gl = s & 1;
      const size_t goff =
          (size_t)((rg32 * 8 + h * 2 + gl) * 2048 + (u & 1) * 1024 + lane * 16);
      const size_t loff = (size_t)(u * 1024 + lane * 16);
      __builtin_amdgcn_global_load_lds(
          (const __attribute__((address_space(1))) unsigned int*)(aBase + goff),
          (__attribute__((address_space(3))) unsigned int*)(As + loff), 16, 0, 0);
      __builtin_amdgcn_global_load_lds(
          (const __attribute__((address_space(1))) unsigned int*)(bBase + goff),
          (__attribute__((address_space(3))) unsigned int*)(Bs + loff), 16, 0, 0);
    }
    __syncthreads();                         // staged data visible

    #pragma unroll
    for (int gl = 0; gl < 2; ++gl) {         // K-64 step within quarter
      i32x8 afr[2], bfr[2];
      #pragma unroll
      for (int rt = 0; rt < 2; ++rt) {
        const unsigned char* p =
            As + (size_t)((wm * 2 + rt) * 2 + gl) * 2048 + lane * 16;
        i32x4 lo = *(const i32x4*)p;
        i32x4 hi = *(const i32x4*)(p + 1024);
        afr[rt][0] = lo[0]; afr[rt][1] = lo[1]; afr[rt][2] = lo[2]; afr[rt][3] = lo[3];
        afr[rt][4] = hi[0]; afr[rt][5] = hi[1]; afr[rt][6] = hi[2]; afr[rt][7] = hi[3];
      }
      #pragma unroll
      for (int ct = 0; ct < 2; ++ct) {
        const unsigned char* p =
            Bs + (size_t)((wn * 2 + ct) * 2 + gl) * 2048 + lane * 16;
        i32x4 lo = *(const i32x4*)p;
        i32x4 hi = *(const i32x4*)(p + 1024);
        bfr[ct][0] = lo[0]; bfr[ct][1] = lo[1]; bfr[ct][2] = lo[2]; bfr[ct][3] = lo[3];
        bfr[ct][4] = hi[0]; bfr[ct][5] = hi[1]; bfr[ct][6] = hi[2]; bfr[ct][7] = hi[3];
      }
      #pragma unroll
      for (int rt = 0; rt < 2; ++rt)
        #pragma unroll
        for (int ct = 0; ct < 2; ++ct)
          acc[rt][ct] = __builtin_amdgcn_mfma_scale_f32_32x32x64_f8f6f4(
              afr[rt], bfr[ct], acc[rt][ct], 0, 0, 0, SCL1, 0, SCL1);
    }
  }

  // ---- epilogue: exp2 -> unique-slot plain LDS writes -> 1 barrier -> stores ----
  // 32x32 C/D layout: col = lane&31, row = (reg&3) + 8*(reg>>2) + 4*(lane>>5)
  const bool posBlk = (bi - bj == 32);  // contains the +B diagonal
  float colpart[2] = {0.f, 0.f};
  #pragma unroll
  for (int rt = 0; rt < 2; ++rt) {
    #pragma unroll
    for (int reg = 0; reg < 16; ++reg) {
      const int lrow = wm * 64 + rt * 32 + (reg & 3) + 8 * (reg >> 2) + 4 * hi5;
      const int grow = rowBlk + lrow;
      float s = 0.f;
      #pragma unroll
      for (int ct = 0; ct < 2; ++ct) {
        const int gcol = colBlk + wn * 64 + ct * 32 + l31;
        float sv = acc[rt][ct][reg];
        float e = exp2f(sv * SCALE2);
        if (isDiag && grow == gcol) e = 0.f;
        if (posBlk && grow - B_ROWS == gcol) pos[gcol] = sv;
        s += e;
        colpart[ct] += e;
      }
      s += __shfl_xor(s, 1);
      s += __shfl_xor(s, 2);
      s += __shfl_xor(s, 4);
      s += __shfl_xor(s, 8);
      s += __shfl_xor(s, 16);
      if (l31 == 0) rp[lrow * 2 + wn] = s;          // single writer per slot
    }
  }
  #pragma unroll
  for (int ct = 0; ct < 2; ++ct) {
    float c = colpart[ct];
    c += __shfl_xor(c, 32);                         // combine row-halves, same col
    if (hi5 == 0) cp[(wn * 64 + ct * 32 + l31) * 2 + wm] = c;  // single writer
  }
  __syncthreads();
  if (tid < 128) {
    scratch[(size_t)(bi * 64 + bj) * 128 + tid] = rp[tid * 2] + rp[tid * 2 + 1];
  } else if (!isDiag) {
    const int c = tid - 128;
    scratch[(size_t)(bj * 64 + bi) * 128 + c] = cp[c * 2] + cp[c * 2 + 1];
  }
}

// ---------------- finalize: rowsum from scratch; loss mean ------------------------
__global__ __launch_bounds__(256) void finalize_kernel(
    const float* __restrict__ scratch, const float* __restrict__ pos,
    float* __restrict__ out) {
  __shared__ float red[4];
  const int gid = blockIdx.x * 256 + threadIdx.x;
  const int band = gid >> 7, r = gid & 127;
  const float* base = scratch + (size_t)band * 64 * 128 + r;
  float s = 0.f;
  #pragma unroll 8
  for (int c = 0; c < 64; ++c) s += base[c * 128];
  float loss = __logf(s) - 2.0f * pos[gid & (B_ROWS - 1)];
  #pragma unroll
  for (int m = 1; m <= 32; m <<= 1) loss += __shfl_xor(loss, m);
  const int wave = threadIdx.x >> 6;
  const int lane = threadIdx.x & 63;
  if (lane == 0) red[wave] = loss;
  __syncthreads();
  if (threadIdx.x == 0)
    atomicAdd(out, (red[0] + red[1] + red[2] + red[3]) * (1.0f / NROWS));
}

extern "C" void kernel_launch(void* const* d_in, const int* in_sizes, int n_in,
                              void* d_out, int out_size, void* d_ws, size_t ws_size,
                              hipStream_t stream) {
  const float* h1 = (const float*)d_in[0];
  const float* h2 = (const float*)d_in[1];
  float* out = (float*)d_out;
  unsigned char* zq = (unsigned char*)d_ws;                        // 4 MiB fp8
  float* scratch = (float*)((char*)d_ws + (size_t)NROWS * DDIM);   // 2 MiB
  float* pos     = scratch + 64 * 64 * 128;                        // 16 KiB

  normalize_kernel<<<NROWS / 32, 256, 0, stream>>>(h1, h2, zq, out);
  simexp_kernel<<<64 * 65 / 2, 256, 0, stream>>>(zq, scratch, pos);
  finalize_kernel<<<NROWS / 256, 256, 0, stream>>>(scratch, pos, out);
}

// Round 3
// 77.557 us; speedup vs baseline: 1.7365x; 1.3663x over previous
//
#include <hip/hip_runtime.h>

typedef int   i32x4  __attribute__((ext_vector_type(4)));
typedef int   i32x8  __attribute__((ext_vector_type(8)));
typedef float f32x16 __attribute__((ext_vector_type(16)));

#define B_ROWS 4096
#define NROWS  8192
#define DDIM   512
// exp(sim/T) = exp2(sim * (1/T)/ln2), T=0.5 -> 2/ln2
#define SCALE2 2.8853900817779268f
// e8m0 scale 127 = 2^0 = 1.0 in every byte -> scaled MFMA == plain fp8 MFMA
#define SCL1   0x7f7f7f7f

// zq layout (v2, bank-conflict-free MX fragments): per 32-row group (rg32 =
// row>>5), 16 KB = 8 k-groups (kg = k>>6) x 2 KB segments. Within a segment,
// lane id l = (k>>5)*32 + (row&31); the lane's 32 fragment bytes are split:
//   bytes k%32 in [0,16)  at  seg +    0 + l*16 + (k&15)
//   bytes k%32 in [16,32) at  seg + 1024 + l*16 + (k&15)
// so an MFMA A/B fragment is TWO LINEAR ds_read_b128 (zero bank conflict,
// verified R2: SQ_LDS_BANK_CONFLICT 2.15M -> 16.6K), and global_load_lds
// staging stays linear (permutation baked into zq by normalize).
// scratch: 64x64 grid of 128-float cells, each written EXACTLY once (row-parts of
// block (bi,bj) -> cell (bi,bj); col-parts -> cell (bj,bi)); no init, no atomics.

// ---------------- normalize: fp32 -> fp8 e4m3, 32-row blocks, LDS-repack ---------
__global__ __launch_bounds__(256) void normalize_kernel(
    const float* __restrict__ h1, const float* __restrict__ h2,
    unsigned char* __restrict__ zq, float* __restrict__ out) {
  __shared__ __align__(16) unsigned char tile[16384];
  if (blockIdx.x == 0 && threadIdx.x == 0) out[0] = 0.0f;

  const int wave = threadIdx.x >> 6;
  const int lane = threadIdx.x & 63;
  const int rb = blockIdx.x;            // 32-row group
  // lane covers k = lane*8 .. lane*8+7
  const int kg = lane >> 3;             // k-group of 64
  const int q  = (lane >> 1) & 1;       // (k>>4)&1: which 16B half-page
  const int h  = (lane >> 2) & 1;       // (k>>5)&1: k-half of 32 (lane-id bit 5)
  const int k8 = (lane & 1) * 8;        // (k&15) byte offset within 16B unit

  #pragma unroll
  for (int it = 0; it < 8; ++it) {
    const int r = it * 4 + wave;        // 0..31, one full row per wave
    const int row = rb * 32 + r;
    const float* src = (row < B_ROWS) ? (h1 + (size_t)row * DDIM)
                                      : (h2 + (size_t)(row - B_ROWS) * DDIM);
    float4 v0 = *(const float4*)(src + lane * 8);
    float4 v1 = *(const float4*)(src + lane * 8 + 4);
    float ss = v0.x*v0.x + v0.y*v0.y + v0.z*v0.z + v0.w*v0.w
             + v1.x*v1.x + v1.y*v1.y + v1.z*v1.z + v1.w*v1.w;
    #pragma unroll
    for (int m = 1; m <= 32; m <<= 1) ss += __shfl_xor(ss, m);
    float sc = 1.0f / fmaxf(sqrtf(ss), 1e-8f);
    int lo = 0, hi = 0;
    lo = __builtin_amdgcn_cvt_pk_fp8_f32(v0.x*sc, v0.y*sc, lo, 0);
    lo = __builtin_amdgcn_cvt_pk_fp8_f32(v0.z*sc, v0.w*sc, lo, 1);
    hi = __builtin_amdgcn_cvt_pk_fp8_f32(v1.x*sc, v1.y*sc, hi, 0);
    hi = __builtin_amdgcn_cvt_pk_fp8_f32(v1.z*sc, v1.w*sc, hi, 1);
    *(int2*)(tile + kg * 2048 + q * 1024 + (h * 32 + r) * 16 + k8) =
        make_int2(lo, hi);
  }
  __syncthreads();
  const size_t base = (size_t)rb * 16384;
  #pragma unroll
  for (int j = 0; j < 4; ++j)
    *(int4*)(zq + base + j * 4096 + threadIdx.x * 16) =
        *(const int4*)(tile + j * 4096 + threadIdx.x * 16);
}

// ---------------- fused sim GEMM (MX-fp8, unit scales) + exp + row-sum ------------
// 32x32x64 scaled MFMA at ~2.3x the non-scaled fp8 rate (4686 vs 2047 TF ubench).
// Register history: (256,4) 128-cap -> 287 MB spill, 121 us. (256,3) 168-cap ->
// STILL 193 MB spill (aligned 16-reg acc tuples + 8-reg frag tuples fragment an
// 84-reg arch pool). Demand is ~150; give it 256 ((256,2), 2 blocks/CU) — zero
// spill beats higher occupancy while spill-BW-bound. Spill canary: WRITE_SIZE.
__global__ __launch_bounds__(256, 2) void simexp_kernel(
    const unsigned char* __restrict__ zq, float* __restrict__ scratch,
    float* __restrict__ pos) {
  __shared__ __align__(16) unsigned char As[16384];  // 8 segs: s = rg32*2 + gl
  __shared__ __align__(16) unsigned char Bs[16384];
  __shared__ float rp[256];   // row partials: slot (lrow)*2 + wn
  __shared__ float cp[256];   // col partials: slot (lcol)*2 + wm

  const int tid  = threadIdx.x;
  const int wave = tid >> 6;
  const int lane = tid & 63;
  const int wm = wave >> 1, wn = wave & 1;
  const int l31 = lane & 31;
  const int hi5 = lane >> 5;

  // unrank triangular block index: t = bi*(bi+1)/2 + bj, bi >= bj
  int t  = blockIdx.x;
  int bi = (int)((sqrtf(8.0f * (float)t + 1.0f) - 1.0f) * 0.5f);
  while ((bi + 1) * (bi + 2) / 2 <= t) ++bi;
  while (bi * (bi + 1) / 2 > t) --bi;
  int bj = t - bi * (bi + 1) / 2;
  const int rowBlk = bi * 128;
  const int colBlk = bj * 128;
  const bool isDiag = (bi == bj);

  const unsigned char* aBase = zq + (size_t)bi * 65536;  // 4 rg32 x 8 kg x 2 KB
  const unsigned char* bBase = zq + (size_t)bj * 65536;

  f32x16 acc[2][2] = {};

  #pragma unroll
  for (int h = 0; h < 4; ++h) {              // K-quarter: kg = h*2, h*2+1
    if (h) __syncthreads();                  // waves done reading previous quarter
    #pragma unroll
    for (int i = 0; i < 4; ++i) {
      const int u = wave * 4 + i;            // 1 KB unit 0..15
      const int s = u >> 1;                  // LDS seg 0..7 = rg32*2 + gl
      const int rg32 = s >> 1, gl = s & 1;
      const size_t goff =
          (size_t)((rg32 * 8 + h * 2 + gl) * 2048 + (u & 1) * 1024 + lane * 16);
      const size_t loff = (size_t)(u * 1024 + lane * 16);
      __builtin_amdgcn_global_load_lds(
          (const __attribute__((address_space(1))) unsigned int*)(aBase + goff),
          (__attribute__((address_space(3))) unsigned int*)(As + loff), 16, 0, 0);
      __builtin_amdgcn_global_load_lds(
          (const __attribute__((address_space(1))) unsigned int*)(bBase + goff),
          (__attribute__((address_space(3))) unsigned int*)(Bs + loff), 16, 0, 0);
    }
    __syncthreads();                         // staged data visible

    #pragma unroll
    for (int gl = 0; gl < 2; ++gl) {         // K-64 step within quarter
      i32x8 afr[2], bfr[2];
      #pragma unroll
      for (int rt = 0; rt < 2; ++rt) {
        const unsigned char* p =
            As + (size_t)((wm * 2 + rt) * 2 + gl) * 2048 + lane * 16;
        i32x4 lo = *(const i32x4*)p;
        i32x4 hi = *(const i32x4*)(p + 1024);
        afr[rt][0] = lo[0]; afr[rt][1] = lo[1]; afr[rt][2] = lo[2]; afr[rt][3] = lo[3];
        afr[rt][4] = hi[0]; afr[rt][5] = hi[1]; afr[rt][6] = hi[2]; afr[rt][7] = hi[3];
      }
      #pragma unroll
      for (int ct = 0; ct < 2; ++ct) {
        const unsigned char* p =
            Bs + (size_t)((wn * 2 + ct) * 2 + gl) * 2048 + lane * 16;
        i32x4 lo = *(const i32x4*)p;
        i32x4 hi = *(const i32x4*)(p + 1024);
        bfr[ct][0] = lo[0]; bfr[ct][1] = lo[1]; bfr[ct][2] = lo[2]; bfr[ct][3] = lo[3];
        bfr[ct][4] = hi[0]; bfr[ct][5] = hi[1]; bfr[ct][6] = hi[2]; bfr[ct][7] = hi[3];
      }
      #pragma unroll
      for (int rt = 0; rt < 2; ++rt)
        #pragma unroll
        for (int ct = 0; ct < 2; ++ct)
          acc[rt][ct] = __builtin_amdgcn_mfma_scale_f32_32x32x64_f8f6f4(
              afr[rt], bfr[ct], acc[rt][ct], 0, 0, 0, SCL1, 0, SCL1);
    }
  }

  // ---- epilogue: exp2 -> unique-slot plain LDS writes -> 1 barrier -> stores ----
  // 32x32 C/D layout: col = lane&31, row = (reg&3) + 8*(reg>>2) + 4*(lane>>5)
  const bool posBlk = (bi - bj == 32);  // contains the +B diagonal
  float colpart[2] = {0.f, 0.f};
  #pragma unroll
  for (int rt = 0; rt < 2; ++rt) {
    #pragma unroll
    for (int reg = 0; reg < 16; ++reg) {
      const int lrow = wm * 64 + rt * 32 + (reg & 3) + 8 * (reg >> 2) + 4 * hi5;
      const int grow = rowBlk + lrow;
      float s = 0.f;
      #pragma unroll
      for (int ct = 0; ct < 2; ++ct) {
        const int gcol = colBlk + wn * 64 + ct * 32 + l31;
        float sv = acc[rt][ct][reg];
        float e = exp2f(sv * SCALE2);
        if (isDiag && grow == gcol) e = 0.f;
        if (posBlk && grow - B_ROWS == gcol) pos[gcol] = sv;
        s += e;
        colpart[ct] += e;
      }
      s += __shfl_xor(s, 1);
      s += __shfl_xor(s, 2);
      s += __shfl_xor(s, 4);
      s += __shfl_xor(s, 8);
      s += __shfl_xor(s, 16);
      if (l31 == 0) rp[lrow * 2 + wn] = s;          // single writer per slot
    }
  }
  #pragma unroll
  for (int ct = 0; ct < 2; ++ct) {
    float c = colpart[ct];
    c += __shfl_xor(c, 32);                         // combine row-halves, same col
    if (hi5 == 0) cp[(wn * 64 + ct * 32 + l31) * 2 + wm] = c;  // single writer
  }
  __syncthreads();
  if (tid < 128) {
    scratch[(size_t)(bi * 64 + bj) * 128 + tid] = rp[tid * 2] + rp[tid * 2 + 1];
  } else if (!isDiag) {
    const int c = tid - 128;
    scratch[(size_t)(bj * 64 + bi) * 128 + c] = cp[c * 2] + cp[c * 2 + 1];
  }
}

// ---------------- finalize: rowsum from scratch; loss mean ------------------------
__global__ __launch_bounds__(256) void finalize_kernel(
    const float* __restrict__ scratch, const float* __restrict__ pos,
    float* __restrict__ out) {
  __shared__ float red[4];
  const int gid = blockIdx.x * 256 + threadIdx.x;
  const int band = gid >> 7, r = gid & 127;
  const float* base = scratch + (size_t)band * 64 * 128 + r;
  float s = 0.f;
  #pragma unroll 8
  for (int c = 0; c < 64; ++c) s += base[c * 128];
  float loss = __logf(s) - 2.0f * pos[gid & (B_ROWS - 1)];
  #pragma unroll
  for (int m = 1; m <= 32; m <<= 1) loss += __shfl_xor(loss, m);
  const int wave = threadIdx.x >> 6;
  const int lane = threadIdx.x & 63;
  if (lane == 0) red[wave] = loss;
  __syncthreads();
  if (threadIdx.x == 0)
    atomicAdd(out, (red[0] + red[1] + red[2] + red[3]) * (1.0f / NROWS));
}

extern "C" void kernel_launch(void* const* d_in, const int* in_sizes, int n_in,
                              void* d_out, int out_size, void* d_ws, size_t ws_size,
                              hipStream_t stream) {
  const float* h1 = (const float*)d_in[0];
  const float* h2 = (const float*)d_in[1];
  float* out = (float*)d_out;
  unsigned char* zq = (unsigned char*)d_ws;                        // 4 MiB fp8
  float* scratch = (float*)((char*)d_ws + (size_t)NROWS * DDIM);   // 2 MiB
  float* pos     = scratch + 64 * 64 * 128;                        // 16 KiB

  normalize_kernel<<<NROWS / 32, 256, 0, stream>>>(h1, h2, zq, out);
  simexp_kernel<<<64 * 65 / 2, 256, 0, stream>>>(zq, scratch, pos);
  finalize_kernel<<<NROWS / 256, 256, 0, stream>>>(scratch, pos, out);
}

// Round 4
// 77.255 us; speedup vs baseline: 1.7433x; 1.0039x over previous
//
#include <hip/hip_runtime.h>

typedef int   i32x4  __attribute__((ext_vector_type(4)));
typedef int   i32x8  __attribute__((ext_vector_type(8)));
typedef float f32x16 __attribute__((ext_vector_type(16)));

#define B_ROWS 4096
#define NROWS  8192
#define DDIM   512
// exp(sim/T) = exp2(sim * (1/T)/ln2), T=0.5 -> 2/ln2
#define SCALE2 2.8853900817779268f
// e8m0 scale 127 = 2^0 = 1.0 in every byte -> scaled MFMA == plain fp8 MFMA
#define SCL1   0x7f7f7f7f

// zq layout (v2, bank-conflict-free MX fragments): per 32-row group (rg32 =
// row>>5), 16 KB = 8 k-groups (kg = k>>6) x 2 KB segments. Within a segment,
// lane id l = (k>>5)*32 + (row&31); the lane's 32 fragment bytes are split:
//   bytes k%32 in [0,16)  at  seg +    0 + l*16 + (k&15)
//   bytes k%32 in [16,32) at  seg + 1024 + l*16 + (k&15)
// so an MFMA A/B fragment is TWO LINEAR ds_read_b128 (zero bank conflict,
// verified R2: SQ_LDS_BANK_CONFLICT 2.15M -> 16.6K), and global_load_lds
// staging stays linear (permutation baked into zq by normalize).
// scratch: 64x64 grid of 128-float cells, each written EXACTLY once (row-parts of
// block (bi,bj) -> cell (bi,bj); col-parts -> cell (bj,bi)); no init, no atomics.

// ---------------- normalize: fp32 -> fp8 e4m3, 32-row blocks, LDS-repack ---------
__global__ __launch_bounds__(256) void normalize_kernel(
    const float* __restrict__ h1, const float* __restrict__ h2,
    unsigned char* __restrict__ zq, float* __restrict__ out) {
  __shared__ __align__(16) unsigned char tile[16384];
  if (blockIdx.x == 0 && threadIdx.x == 0) out[0] = 0.0f;

  const int wave = threadIdx.x >> 6;
  const int lane = threadIdx.x & 63;
  const int rb = blockIdx.x;            // 32-row group
  // lane covers k = lane*8 .. lane*8+7
  const int kg = lane >> 3;             // k-group of 64
  const int q  = (lane >> 1) & 1;       // (k>>4)&1: which 16B half-page
  const int h  = (lane >> 2) & 1;       // (k>>5)&1: k-half of 32 (lane-id bit 5)
  const int k8 = (lane & 1) * 8;        // (k&15) byte offset within 16B unit

  #pragma unroll
  for (int it = 0; it < 8; ++it) {
    const int r = it * 4 + wave;        // 0..31, one full row per wave
    const int row = rb * 32 + r;
    const float* src = (row < B_ROWS) ? (h1 + (size_t)row * DDIM)
                                      : (h2 + (size_t)(row - B_ROWS) * DDIM);
    float4 v0 = *(const float4*)(src + lane * 8);
    float4 v1 = *(const float4*)(src + lane * 8 + 4);
    float ss = v0.x*v0.x + v0.y*v0.y + v0.z*v0.z + v0.w*v0.w
             + v1.x*v1.x + v1.y*v1.y + v1.z*v1.z + v1.w*v1.w;
    #pragma unroll
    for (int m = 1; m <= 32; m <<= 1) ss += __shfl_xor(ss, m);
    float sc = 1.0f / fmaxf(sqrtf(ss), 1e-8f);
    int lo = 0, hi = 0;
    lo = __builtin_amdgcn_cvt_pk_fp8_f32(v0.x*sc, v0.y*sc, lo, 0);
    lo = __builtin_amdgcn_cvt_pk_fp8_f32(v0.z*sc, v0.w*sc, lo, 1);
    hi = __builtin_amdgcn_cvt_pk_fp8_f32(v1.x*sc, v1.y*sc, hi, 0);
    hi = __builtin_amdgcn_cvt_pk_fp8_f32(v1.z*sc, v1.w*sc, hi, 1);
    *(int2*)(tile + kg * 2048 + q * 1024 + (h * 32 + r) * 16 + k8) =
        make_int2(lo, hi);
  }
  __syncthreads();
  const size_t base = (size_t)rb * 16384;
  #pragma unroll
  for (int j = 0; j < 4; ++j)
    *(int4*)(zq + base + j * 4096 + threadIdx.x * 16) =
        *(const int4*)(tile + j * 4096 + threadIdx.x * 16);
}

// ---------------- fused sim GEMM (MX-fp8, unit scales) + exp + row-sum ------------
// 32x32x64 scaled MFMA at ~2.3x the non-scaled fp8 rate. Register history:
// (256,4)->287MB spill; (256,3)->193MB spill; (256,2)->0 spill (R3, 2.06MB WRITE).
// R3 was latency-bound (MfmaUtil 9.7%, VALU 23%, HBM 3.7%): __syncthreads drains
// vmcnt(0) 8x per block with only 2 blocks/CU to overlap. Fix = T3/T4 minimum
// 2-phase pipeline: LDS double-buffer + raw s_barrier + counted vmcnt(8) so the
// next K-quarter's 8 loads stay in flight across this quarter's MFMAs.
#define ASM_VMCNT8() asm volatile("s_waitcnt vmcnt(8)" ::: "memory")
#define ASM_VMCNT0() asm volatile("s_waitcnt vmcnt(0)" ::: "memory")
#define BARRIER() do { asm volatile("" ::: "memory"); \
                       __builtin_amdgcn_s_barrier(); \
                       asm volatile("" ::: "memory"); } while (0)

__global__ __launch_bounds__(256, 2) void simexp_kernel(
    const unsigned char* __restrict__ zq, float* __restrict__ scratch,
    float* __restrict__ pos) {
  __shared__ __align__(16) unsigned char As[32768];  // 2 bufs x 8 segs
  __shared__ __align__(16) unsigned char Bs[32768];
  __shared__ float rp[256];   // row partials: slot (lrow)*2 + wn
  __shared__ float cp[256];   // col partials: slot (lcol)*2 + wm

  const int tid  = threadIdx.x;
  const int wave = tid >> 6;
  const int lane = tid & 63;
  const int wm = wave >> 1, wn = wave & 1;
  const int l31 = lane & 31;
  const int hi5 = lane >> 5;

  // unrank triangular block index: t = bi*(bi+1)/2 + bj, bi >= bj
  int t  = blockIdx.x;
  int bi = (int)((sqrtf(8.0f * (float)t + 1.0f) - 1.0f) * 0.5f);
  while ((bi + 1) * (bi + 2) / 2 <= t) ++bi;
  while (bi * (bi + 1) / 2 > t) --bi;
  int bj = t - bi * (bi + 1) / 2;
  const int rowBlk = bi * 128;
  const int colBlk = bj * 128;
  const bool isDiag = (bi == bj);

  const unsigned char* aBase = zq + (size_t)bi * 65536;  // 4 rg32 x 8 kg x 2 KB
  const unsigned char* bBase = zq + (size_t)bj * 65536;

  f32x16 acc[2][2] = {};

  // 8 global_load_lds per wave per quarter (4 units x {A,B})
  #define STAGE(hh, bb) do {                                                   \
    _Pragma("unroll")                                                          \
    for (int i = 0; i < 4; ++i) {                                              \
      const int u = wave * 4 + i;                                              \
      const int s = u >> 1;                                                    \
      const int rg32 = s >> 1, gl = s & 1;                                     \
      const size_t goff =                                                      \
          (size_t)((rg32 * 8 + (hh) * 2 + gl) * 2048 + (u & 1) * 1024 + lane * 16); \
      const size_t loff = (size_t)((bb) * 16384 + u * 1024 + lane * 16);       \
      __builtin_amdgcn_global_load_lds(                                        \
          (const __attribute__((address_space(1))) unsigned int*)(aBase + goff), \
          (__attribute__((address_space(3))) unsigned int*)(As + loff), 16, 0, 0); \
      __builtin_amdgcn_global_load_lds(                                        \
          (const __attribute__((address_space(1))) unsigned int*)(bBase + goff), \
          (__attribute__((address_space(3))) unsigned int*)(Bs + loff), 16, 0, 0); \
    }                                                                          \
  } while (0)

  STAGE(0, 0);
  #pragma unroll
  for (int h = 0; h < 4; ++h) {              // K-quarter: kg = h*2, h*2+1
    if (h < 3) {
      STAGE(h + 1, (h + 1) & 1);
      ASM_VMCNT8();                          // quarter-h loads landed; h+1 in flight
    } else {
      ASM_VMCNT0();
    }
    BARRIER();                               // buf[h&1] visible to all waves

    const int bb = (h & 1) * 16384;
    #pragma unroll
    for (int gl = 0; gl < 2; ++gl) {         // K-64 step within quarter
      i32x8 afr[2], bfr[2];
      #pragma unroll
      for (int rt = 0; rt < 2; ++rt) {
        const unsigned char* p =
            As + bb + (size_t)((wm * 2 + rt) * 2 + gl) * 2048 + lane * 16;
        i32x4 lo = *(const i32x4*)p;
        i32x4 hi = *(const i32x4*)(p + 1024);
        afr[rt][0] = lo[0]; afr[rt][1] = lo[1]; afr[rt][2] = lo[2]; afr[rt][3] = lo[3];
        afr[rt][4] = hi[0]; afr[rt][5] = hi[1]; afr[rt][6] = hi[2]; afr[rt][7] = hi[3];
      }
      #pragma unroll
      for (int ct = 0; ct < 2; ++ct) {
        const unsigned char* p =
            Bs + bb + (size_t)((wn * 2 + ct) * 2 + gl) * 2048 + lane * 16;
        i32x4 lo = *(const i32x4*)p;
        i32x4 hi = *(const i32x4*)(p + 1024);
        bfr[ct][0] = lo[0]; bfr[ct][1] = lo[1]; bfr[ct][2] = lo[2]; bfr[ct][3] = lo[3];
        bfr[ct][4] = hi[0]; bfr[ct][5] = hi[1]; bfr[ct][6] = hi[2]; bfr[ct][7] = hi[3];
      }
      #pragma unroll
      for (int rt = 0; rt < 2; ++rt)
        #pragma unroll
        for (int ct = 0; ct < 2; ++ct)
          acc[rt][ct] = __builtin_amdgcn_mfma_scale_f32_32x32x64_f8f6f4(
              afr[rt], bfr[ct], acc[rt][ct], 0, 0, 0, SCL1, 0, SCL1);
    }
    // lgkmcnt waits feeding the MFMAs guarantee our ds_reads completed, so
    // after this barrier buf[h&1] is safe to overwrite by STAGE(h+2).
    if (h < 3) BARRIER();
  }

  // ---- epilogue: exp2 -> unique-slot plain LDS writes -> 1 barrier -> stores ----
  // 32x32 C/D layout: col = lane&31, row = (reg&3) + 8*(reg>>2) + 4*(lane>>5)
  const bool posBlk = (bi - bj == 32);  // contains the +B diagonal
  float colpart[2] = {0.f, 0.f};
  #pragma unroll
  for (int rt = 0; rt < 2; ++rt) {
    #pragma unroll
    for (int reg = 0; reg < 16; ++reg) {
      const int lrow = wm * 64 + rt * 32 + (reg & 3) + 8 * (reg >> 2) + 4 * hi5;
      const int grow = rowBlk + lrow;
      float s = 0.f;
      #pragma unroll
      for (int ct = 0; ct < 2; ++ct) {
        const int gcol = colBlk + wn * 64 + ct * 32 + l31;
        float sv = acc[rt][ct][reg];
        float e = exp2f(sv * SCALE2);
        if (isDiag && grow == gcol) e = 0.f;
        if (posBlk && grow - B_ROWS == gcol) pos[gcol] = sv;
        s += e;
        colpart[ct] += e;
      }
      s += __shfl_xor(s, 1);
      s += __shfl_xor(s, 2);
      s += __shfl_xor(s, 4);
      s += __shfl_xor(s, 8);
      s += __shfl_xor(s, 16);
      if (l31 == 0) rp[lrow * 2 + wn] = s;          // single writer per slot
    }
  }
  #pragma unroll
  for (int ct = 0; ct < 2; ++ct) {
    float c = colpart[ct];
    c += __shfl_xor(c, 32);                         // combine row-halves, same col
    if (hi5 == 0) cp[(wn * 64 + ct * 32 + l31) * 2 + wm] = c;  // single writer
  }
  __syncthreads();
  if (tid < 128) {
    scratch[(size_t)(bi * 64 + bj) * 128 + tid] = rp[tid * 2] + rp[tid * 2 + 1];
  } else if (!isDiag) {
    const int c = tid - 128;
    scratch[(size_t)(bj * 64 + bi) * 128 + c] = cp[c * 2] + cp[c * 2 + 1];
  }
}

// ---------------- finalize: rowsum from scratch; loss mean ------------------------
__global__ __launch_bounds__(256) void finalize_kernel(
    const float* __restrict__ scratch, const float* __restrict__ pos,
    float* __restrict__ out) {
  __shared__ float red[4];
  const int gid = blockIdx.x * 256 + threadIdx.x;
  const int band = gid >> 7, r = gid & 127;
  const float* base = scratch + (size_t)band * 64 * 128 + r;
  float s = 0.f;
  #pragma unroll 8
  for (int c = 0; c < 64; ++c) s += base[c * 128];
  float loss = __logf(s) - 2.0f * pos[gid & (B_ROWS - 1)];
  #pragma unroll
  for (int m = 1; m <= 32; m <<= 1) loss += __shfl_xor(loss, m);
  const int wave = threadIdx.x >> 6;
  const int lane = threadIdx.x & 63;
  if (lane == 0) red[wave] = loss;
  __syncthreads();
  if (threadIdx.x == 0)
    atomicAdd(out, (red[0] + red[1] + red[2] + red[3]) * (1.0f / NROWS));
}

extern "C" void kernel_launch(void* const* d_in, const int* in_sizes, int n_in,
                              void* d_out, int out_size, void* d_ws, size_t ws_size,
                              hipStream_t stream) {
  const float* h1 = (const float*)d_in[0];
  const float* h2 = (const float*)d_in[1];
  float* out = (float*)d_out;
  unsigned char* zq = (unsigned char*)d_ws;                        // 4 MiB fp8
  float* scratch = (float*)((char*)d_ws + (size_t)NROWS * DDIM);   // 2 MiB
  float* pos     = scratch + 64 * 64 * 128;                        // 16 KiB

  normalize_kernel<<<NROWS / 32, 256, 0, stream>>>(h1, h2, zq, out);
  simexp_kernel<<<64 * 65 / 2, 256, 0, stream>>>(zq, scratch, pos);
  finalize_kernel<<<NROWS / 256, 256, 0, stream>>>(scratch, pos, out);
}